// Round 13
// baseline (317.111 us; speedup 1.0000x reference)
//
#include <hip/hip_runtime.h>
#include <math.h>

// Problem constants
#define BB 8
#define CC 64
#define TT 512
#define FF 256

typedef float floatx4 __attribute__((ext_vector_type(4)));

constexpr int TOFF = BB * FF;                       // 2048
constexpr int COFF = BB * FF + BB * TT;             // 6144
constexpr int NSUM = BB * FF + BB * TT + BB * CC;   // 6656 floats

// ws layout (floats)
constexpr long PF_OFF = 0;                          // Pfreq [4096][256]
constexpr long PT_OFF = PF_OFF + 4096L * 256;       // Ptime [4096][64]
constexpr long PC_OFF = PT_OFF + 4096L * 64;        // Pch   [4096]
constexpr long G_OFF  = PC_OFF + 4096;              // gates [NSUM]

// ---------------------------------------------------------------------------
// R13 DECOMPOSITION ROUND: kernels are EXACT R7 (203.9us anchor).
// gate_k launched 3x (idempotent) => R13 - R7 = 2*(gate_hot + boundary).
// Splits R7's unexplained 77us residual into {gate} vs {fixed overhead}.
// ---------------------------------------------------------------------------

__global__ __launch_bounds__(256) void pool_k(const float* __restrict__ x,
                                              float* __restrict__ pf,
                                              float* __restrict__ pt,
                                              float* __restrict__ pc) {
    __shared__ float tr[16][257];
    __shared__ float fr[256];
    __shared__ float cw[4];
    const int tid  = threadIdx.x;
    const int lane = tid & 63;
    const int wid  = tid >> 6;
    const int chunk = blockIdx.x;                    // 0..4095

    const floatx4* __restrict__ x4 = (const floatx4*)x;
    const long base = (long)chunk * 4096 + wid * 1024 + lane;

    float a0 = 0.f, a1 = 0.f, a2 = 0.f, a3 = 0.f;    // freq partials
    float ach[16];                                   // row sums (time)
    #pragma unroll
    for (int k = 0; k < 16; ++k) {
        floatx4 d = x4[base + k * 64];               // temporal: fill L3
        a0 += d.x; a1 += d.y; a2 += d.z; a3 += d.w;
        ach[k] = (d.x + d.y) + (d.z + d.w);
    }
    float csum = 0.f;
    #pragma unroll
    for (int k = 0; k < 16; ++k) csum += ach[k];
    #pragma unroll
    for (int o = 32; o > 0; o >>= 1) csum += __shfl_xor(csum, o, 64);

    fr[tid] = 0.f;
    #pragma unroll
    for (int k = 0; k < 16; ++k) tr[k][tid] = ach[k];
    if (lane == 0) cw[wid] = csum;
    __syncthreads();

    atomicAdd(&fr[4 * lane + 0], a0);
    atomicAdd(&fr[4 * lane + 1], a1);
    atomicAdd(&fr[4 * lane + 2], a2);
    atomicAdd(&fr[4 * lane + 3], a3);

    {   // time: row s of chunk summed by 4 threads (q), then 2 shuffles
        const int s = tid >> 2, q = tid & 3;
        float v = 0.f;
        #pragma unroll
        for (int j = 0; j < 16; ++j)
            v += tr[s & 15][(s >> 4) * 64 + q * 16 + j];
        v += __shfl_xor(v, 1, 64);
        v += __shfl_xor(v, 2, 64);
        if (q == 0) pt[chunk * 64 + s] = v;          // plain store
    }
    __syncthreads();

    pf[chunk * 256 + tid] = fr[tid];                 // plain store
    if (tid == 0) pc[chunk] = (cw[0] + cw[1]) + (cw[2] + cw[3]);
}

__global__ __launch_bounds__(512) void gate_k(
    const float* __restrict__ w1f, const float* __restrict__ w2f,
    const float* __restrict__ w1t, const float* __restrict__ w2t,
    const float* __restrict__ w1c, const float* __restrict__ w2c,
    const float* __restrict__ pf, const float* __restrict__ pt,
    const float* __restrict__ pc, float* __restrict__ gates) {
    __shared__ __align__(16) float s[512];
    __shared__ __align__(16) float h[512];
    const int g = blockIdx.x >> 3;
    const int b = blockIdx.x & 7;
    const int tid = threadIdx.x;

    int dim; const float *w1, *w2; float* gout; float inv;
    if (g == 0) { dim = FF; w1 = w1f; w2 = w2f; gout = gates + b * FF;
                  inv = 1.f / (float)(CC * TT); }
    else if (g == 1) { dim = TT; w1 = w1t; w2 = w2t; gout = gates + TOFF + b * TT;
                  inv = 1.f / (float)(CC * FF); }
    else { dim = CC; w1 = w1c; w2 = w2c; gout = gates + COFF + b * CC;
                  inv = 1.f / (float)(TT * FF); }

    if (g == 0) {
        const int f = tid & 255, half = tid >> 8;
        float acc = 0.f;
        const float* __restrict__ p = pf + ((long)(b * 512 + half * 256) * 256) + f;
        #pragma unroll 8
        for (int ch = 0; ch < 256; ++ch) acc += p[(long)ch * 256];
        h[tid] = acc;
        __syncthreads();
        if (tid < 256) s[tid] = (h[tid] + h[tid + 256]) * inv;
    } else if (g == 1) {
        const int t = tid;
        float acc = 0.f;
        const float* __restrict__ p = pt + ((long)(b * 512 + (t >> 6)) * 64) + (t & 63);
        #pragma unroll 8
        for (int c = 0; c < 64; ++c) acc += p[(long)c * 8 * 64];
        s[t] = acc * inv;
    } else {
        if (tid < CC) {
            float acc = 0.f;
            #pragma unroll
            for (int j = 0; j < 8; ++j) acc += pc[b * 512 + tid * 8 + j];
            s[tid] = acc * inv;
        }
    }
    __syncthreads();

    for (int row = tid; row < dim; row += 512) {
        const floatx4* __restrict__ wr = (const floatx4*)(w1 + (long)row * dim);
        const floatx4* __restrict__ sv = (const floatx4*)s;
        float c0 = 0.f, c1 = 0.f, c2 = 0.f, c3 = 0.f;
        for (int j = 0; j < dim / 4; ++j) {
            floatx4 w = wr[j]; floatx4 sj = sv[j];
            c0 += w.x * sj.x; c1 += w.y * sj.y; c2 += w.z * sj.z; c3 += w.w * sj.w;
        }
        h[row] = fmaxf((c0 + c1) + (c2 + c3), 0.f);
    }
    __syncthreads();
    for (int row = tid; row < dim; row += 512) {
        const floatx4* __restrict__ wr = (const floatx4*)(w2 + (long)row * dim);
        const floatx4* __restrict__ hv = (const floatx4*)h;
        float c0 = 0.f, c1 = 0.f, c2 = 0.f, c3 = 0.f;
        for (int j = 0; j < dim / 4; ++j) {
            floatx4 w = wr[j]; floatx4 hj = hv[j];
            c0 += w.x * hj.x; c1 += w.y * hj.y; c2 += w.z * hj.z; c3 += w.w * hj.w;
        }
        gout[row] = 1.f / (1.f + expf(-((c0 + c1) + (c2 + c3))));
    }
}

__global__ __launch_bounds__(256) void apply_k(const float* __restrict__ x,
                                               const float* __restrict__ gts,
                                               float* __restrict__ out) {
    const floatx4* __restrict__ x4 = (const floatx4*)x;
    floatx4* __restrict__ o4 = (floatx4*)out;
    const long base3 = (long)blockIdx.x * 256 + threadIdx.x;   // < 2^19
    const int f4 = (int)(base3 & 63);
    const int t  = (int)((base3 >> 6) & (TT - 1));
    const int cb = (int)((base3 >> 15) & (CC - 1));
    #pragma unroll 8
    for (int k = 31; k >= 0; --k) {
        const int b = k >> 2;
        const int c = (cb + k * 16) & (CC - 1);
        const floatx4 fm = ((const floatx4*)(gts + b * FF))[f4];
        const float gadd = gts[TOFF + b * TT + t]
                         + gts[COFF + b * CC + c] + 1.0f;
        const long v = base3 + ((long)k << 19);
        floatx4 d = x4[v];                           // mostly L3 hits
        floatx4 o = d * (fm + gadd);
        __builtin_nontemporal_store(o, &o4[v]);
    }
}

extern "C" void kernel_launch(void* const* d_in, const int* in_sizes, int n_in,
                              void* d_out, int out_size, void* d_ws, size_t ws_size,
                              hipStream_t stream) {
    const float* x   = (const float*)d_in[0];
    const float* w1f = (const float*)d_in[1];
    const float* w2f = (const float*)d_in[2];
    const float* w1t = (const float*)d_in[3];
    const float* w2t = (const float*)d_in[4];
    const float* w1c = (const float*)d_in[5];
    const float* w2c = (const float*)d_in[6];
    float* out = (float*)d_out;

    float* ws    = (float*)d_ws;
    float* pf    = ws + PF_OFF;
    float* pt    = ws + PT_OFF;
    float* pc    = ws + PC_OFF;
    float* gates = ws + G_OFF;

    pool_k<<<4096, 256, 0, stream>>>(x, pf, pt, pc);
    // R13 experiment: gate_k x3 (idempotent) to isolate gate_hot + boundary.
    gate_k<<<24, 512, 0, stream>>>(w1f, w2f, w1t, w2t, w1c, w2c,
                                   pf, pt, pc, gates);
    gate_k<<<24, 512, 0, stream>>>(w1f, w2f, w1t, w2t, w1c, w2c,
                                   pf, pt, pc, gates);
    gate_k<<<24, 512, 0, stream>>>(w1f, w2f, w1t, w2t, w1c, w2c,
                                   pf, pt, pc, gates);
    apply_k<<<2048, 256, 0, stream>>>(x, gates, out);
}

// Round 14
// 253.244 us; speedup vs baseline: 1.2522x; 1.2522x over previous
//
#include <hip/hip_runtime.h>
#include <math.h>

// Problem constants
#define BB 8
#define CC 64
#define TT 512
#define FF 256

typedef float floatx4 __attribute__((ext_vector_type(4)));

constexpr int TOFF = BB * FF;                       // 2048
constexpr int COFF = BB * FF + BB * TT;             // 6144
constexpr int NSUM = BB * FF + BB * TT + BB * CC;   // 6656 floats

// ws layout (floats)
constexpr long PF_OFF  = 0;                         // Pfreq [4096][256]
constexpr long PT_OFF  = PF_OFF + 4096L * 256;      // Ptime [4096][64]
constexpr long PC_OFF  = PT_OFF + 4096L * 64;       // Pch   [4096]
constexpr long G_OFF   = PC_OFF + 4096;             // gates [NSUM]
constexpr long CNT_OFF = G_OFF + NSUM;              // 24 u64 (offset even -> 8B aligned)

struct PoolShm { float tr[16][257]; float fr[256]; float cw[4]; }; // 17.5 KB
struct GateShm { float s[512]; float h[512]; };                    //  4 KB
union  Shm { PoolShm p; GateShm g; };

// Agent-scope atomic load: read from the device coherence point (L3),
// bypassing possibly-stale XCD-local cache state.
__device__ __forceinline__ float aload(const float* p) {
    return __hip_atomic_load(p, __ATOMIC_RELAXED, __HIP_MEMORY_SCOPE_AGENT);
}

// ---------------------------------------------------------------------------
// Gate tails (R10/R11-verified math; partials read via agent-scope loads).
// Each runs on ONE winner block (256 threads) for one (batch, gate-unit).
// ---------------------------------------------------------------------------
__device__ void tail_f(const float* __restrict__ w1f, const float* __restrict__ w2f,
                       const float* __restrict__ pf, float* __restrict__ gates,
                       GateShm& gs, int b, int tid) {
    float a[8];
    #pragma unroll
    for (int i = 0; i < 8; ++i) a[i] = 0.f;
    const float* p = pf + (long)(b * 512) * 256 + tid;
    #pragma unroll 2
    for (int ch = 0; ch < 512; ch += 8) {
        #pragma unroll
        for (int i = 0; i < 8; ++i) a[i] += aload(&p[(long)(ch + i) * 256]);
    }
    gs.s[tid] = (((a[0] + a[1]) + (a[2] + a[3])) + ((a[4] + a[5]) + (a[6] + a[7])))
              * (1.f / (float)(CC * TT));
    __syncthreads();
    {
        const floatx4* wr = (const floatx4*)(w1f + (long)tid * FF);
        const floatx4* sv = (const floatx4*)gs.s;
        float c0 = 0.f, c1 = 0.f, c2 = 0.f, c3 = 0.f;
        for (int j = 0; j < FF / 4; ++j) {
            floatx4 w = wr[j], v = sv[j];
            c0 += w.x * v.x; c1 += w.y * v.y; c2 += w.z * v.z; c3 += w.w * v.w;
        }
        gs.h[tid] = fmaxf((c0 + c1) + (c2 + c3), 0.f);
    }
    __syncthreads();
    {
        const floatx4* wr = (const floatx4*)(w2f + (long)tid * FF);
        const floatx4* hv = (const floatx4*)gs.h;
        float c0 = 0.f, c1 = 0.f, c2 = 0.f, c3 = 0.f;
        for (int j = 0; j < FF / 4; ++j) {
            floatx4 w = wr[j], v = hv[j];
            c0 += w.x * v.x; c1 += w.y * v.y; c2 += w.z * v.z; c3 += w.w * v.w;
        }
        gates[b * FF + tid] = 1.f / (1.f + expf(-((c0 + c1) + (c2 + c3))));
    }
}

__device__ void tail_t(const float* __restrict__ w1t, const float* __restrict__ w2t,
                       const float* __restrict__ pt, float* __restrict__ gates,
                       GateShm& gs, int b, int tid) {
    #pragma unroll
    for (int r = 0; r < 2; ++r) {
        const int t2 = tid + r * 256;
        const float* p = pt + (long)(b * 512 + (t2 >> 6)) * 64 + (t2 & 63);
        float a0 = 0.f, a1 = 0.f, a2 = 0.f, a3 = 0.f;
        #pragma unroll 4
        for (int c = 0; c < 64; c += 4) {
            a0 += aload(&p[(long)(c + 0) * 512]);
            a1 += aload(&p[(long)(c + 1) * 512]);
            a2 += aload(&p[(long)(c + 2) * 512]);
            a3 += aload(&p[(long)(c + 3) * 512]);
        }
        gs.s[t2] = ((a0 + a1) + (a2 + a3)) * (1.f / (float)(CC * FF));
    }
    __syncthreads();
    #pragma unroll
    for (int r = 0; r < 2; ++r) {
        const int row = tid + r * 256;
        const floatx4* wr = (const floatx4*)(w1t + (long)row * TT);
        const floatx4* sv = (const floatx4*)gs.s;
        float c0 = 0.f, c1 = 0.f, c2 = 0.f, c3 = 0.f;
        for (int j = 0; j < TT / 4; ++j) {
            floatx4 w = wr[j], v = sv[j];
            c0 += w.x * v.x; c1 += w.y * v.y; c2 += w.z * v.z; c3 += w.w * v.w;
        }
        gs.h[row] = fmaxf((c0 + c1) + (c2 + c3), 0.f);
    }
    __syncthreads();
    #pragma unroll
    for (int r = 0; r < 2; ++r) {
        const int row = tid + r * 256;
        const floatx4* wr = (const floatx4*)(w2t + (long)row * TT);
        const floatx4* hv = (const floatx4*)gs.h;
        float c0 = 0.f, c1 = 0.f, c2 = 0.f, c3 = 0.f;
        for (int j = 0; j < TT / 4; ++j) {
            floatx4 w = wr[j], v = hv[j];
            c0 += w.x * v.x; c1 += w.y * v.y; c2 += w.z * v.z; c3 += w.w * v.w;
        }
        gates[TOFF + b * TT + row] = 1.f / (1.f + expf(-((c0 + c1) + (c2 + c3))));
    }
}

__device__ void tail_c(const float* __restrict__ w1c, const float* __restrict__ w2c,
                       const float* __restrict__ pc, float* __restrict__ gates,
                       GateShm& gs, int b, int tid) {
    if (tid < CC) {
        float acc = 0.f;
        #pragma unroll
        for (int j = 0; j < 8; ++j) acc += aload(&pc[b * 512 + tid * 8 + j]);
        gs.s[tid] = acc * (1.f / (float)(TT * FF));
    }
    __syncthreads();
    if (tid < CC) {
        const floatx4* wr = (const floatx4*)(w1c + (long)tid * CC);
        const floatx4* sv = (const floatx4*)gs.s;
        float c0 = 0.f, c1 = 0.f, c2 = 0.f, c3 = 0.f;
        for (int j = 0; j < CC / 4; ++j) {
            floatx4 w = wr[j], v = sv[j];
            c0 += w.x * v.x; c1 += w.y * v.y; c2 += w.z * v.z; c3 += w.w * v.w;
        }
        gs.h[tid] = fmaxf((c0 + c1) + (c2 + c3), 0.f);
    }
    __syncthreads();
    if (tid < CC) {
        const floatx4* wr = (const floatx4*)(w2c + (long)tid * CC);
        const floatx4* hv = (const floatx4*)gs.h;
        float c0 = 0.f, c1 = 0.f, c2 = 0.f, c3 = 0.f;
        for (int j = 0; j < CC / 4; ++j) {
            floatx4 w = wr[j], v = hv[j];
            c0 += w.x * v.x; c1 += w.y * v.y; c2 += w.z * v.z; c3 += w.w * v.w;
        }
        gates[COFF + b * CC + tid] = 1.f / (1.f + expf(-((c0 + c1) + (c2 + c3))));
    }
}

// ---------------------------------------------------------------------------
// Kernel 1: pool + fence-free gate tail.
// Pool body = R7-verified; partials published via atomicExch (memory-side,
// cross-XCD coherent — NO __threadfence, R11 lesson) + s_waitcnt(0) drain.
// Election: garbage-proof mod-512 ticket on a u64 counter — exactly one
// winner per (b,g) regardless of counter's initial value (no zeroing pass,
// no waiting, no polling; R8/R10 lesson). Winner (the 512th arriver => all
// of batch b's partials performed) computes that gate unit.
// ---------------------------------------------------------------------------
__global__ __launch_bounds__(256) void pool_gate_k(
    const float* __restrict__ x,
    const float* __restrict__ w1f, const float* __restrict__ w2f,
    const float* __restrict__ w1t, const float* __restrict__ w2t,
    const float* __restrict__ w1c, const float* __restrict__ w2c,
    float* __restrict__ pf, float* __restrict__ pt, float* __restrict__ pc,
    float* __restrict__ gates, unsigned long long* __restrict__ cnt)
{
    __shared__ Shm u;
    __shared__ int winf[3];
    const int tid  = threadIdx.x;
    const int lane = tid & 63;
    const int wid  = tid >> 6;
    const int chunk = blockIdx.x;                    // 0..4095
    const int b     = chunk >> 9;

    const floatx4* __restrict__ x4 = (const floatx4*)x;
    const long base = (long)chunk * 4096 + wid * 1024 + lane;

    float a0 = 0.f, a1 = 0.f, a2 = 0.f, a3 = 0.f;    // freq partials
    float ach[16];                                   // row sums (time)
    #pragma unroll
    for (int k = 0; k < 16; ++k) {
        floatx4 d = x4[base + k * 64];               // temporal: fill L3
        a0 += d.x; a1 += d.y; a2 += d.z; a3 += d.w;
        ach[k] = (d.x + d.y) + (d.z + d.w);
    }
    float csum = 0.f;
    #pragma unroll
    for (int k = 0; k < 16; ++k) csum += ach[k];
    #pragma unroll
    for (int o = 32; o > 0; o >>= 1) csum += __shfl_xor(csum, o, 64);

    u.p.fr[tid] = 0.f;
    #pragma unroll
    for (int k = 0; k < 16; ++k) u.p.tr[k][tid] = ach[k];
    if (lane == 0) u.p.cw[wid] = csum;
    __syncthreads();

    atomicAdd(&u.p.fr[4 * lane + 0], a0);
    atomicAdd(&u.p.fr[4 * lane + 1], a1);
    atomicAdd(&u.p.fr[4 * lane + 2], a2);
    atomicAdd(&u.p.fr[4 * lane + 3], a3);

    {   // time: row s of chunk summed by 4 threads (q), then 2 shuffles
        const int s = tid >> 2, q = tid & 3;
        float v = 0.f;
        #pragma unroll
        for (int j = 0; j < 16; ++j)
            v += u.p.tr[s & 15][(s >> 4) * 64 + q * 16 + j];
        v += __shfl_xor(v, 1, 64);
        v += __shfl_xor(v, 2, 64);
        if (q == 0) atomicExch(&pt[chunk * 64 + s], v);   // memory-side store
    }
    __syncthreads();

    atomicExch(&pf[chunk * 256 + tid], u.p.fr[tid]);      // memory-side store
    if (tid == 0)
        atomicExch(&pc[chunk],
                   (u.p.cw[0] + u.p.cw[1]) + (u.p.cw[2] + u.p.cw[3]));

    // drain: all this thread's exchanges performed at the coherence point
    __builtin_amdgcn_s_waitcnt(0);
    __syncthreads();

    // ---- election: exactly one winner per (b,g), init-value-proof ----
    if (tid < 3) {
        unsigned long long old = atomicAdd(&cnt[b * 3 + tid], 1ULL);
        winf[tid] = (((old + 1) & 511ULL) == 0ULL);
    }
    __syncthreads();

    if (winf[0]) { tail_f(w1f, w2f, pf, gates, u.g, b, tid); __syncthreads(); }
    if (winf[1]) { tail_t(w1t, w2t, pt, gates, u.g, b, tid); __syncthreads(); }
    if (winf[2]) { tail_c(w1c, w2c, pc, gates, u.g, b, tid); }
}

// ---------------------------------------------------------------------------
// Kernel 2: apply (R7-verified, byte-identical). Descending order chases
// pool's MRU L3 content (R6: ~94% L3 hits); nt stores spare x eviction.
// The kernel boundary publishes the winners' gate stores.
// ---------------------------------------------------------------------------
__global__ __launch_bounds__(256) void apply_k(const float* __restrict__ x,
                                               const float* __restrict__ gts,
                                               float* __restrict__ out) {
    const floatx4* __restrict__ x4 = (const floatx4*)x;
    floatx4* __restrict__ o4 = (floatx4*)out;
    const long base3 = (long)blockIdx.x * 256 + threadIdx.x;   // < 2^19
    const int f4 = (int)(base3 & 63);
    const int t  = (int)((base3 >> 6) & (TT - 1));
    const int cb = (int)((base3 >> 15) & (CC - 1));
    #pragma unroll 8
    for (int k = 31; k >= 0; --k) {
        const int b = k >> 2;
        const int c = (cb + k * 16) & (CC - 1);
        const floatx4 fm = ((const floatx4*)(gts + b * FF))[f4];
        const float gadd = gts[TOFF + b * TT + t]
                         + gts[COFF + b * CC + c] + 1.0f;
        const long v = base3 + ((long)k << 19);
        floatx4 d = x4[v];                           // mostly L3 hits
        floatx4 o = d * (fm + gadd);
        __builtin_nontemporal_store(o, &o4[v]);
    }
}

extern "C" void kernel_launch(void* const* d_in, const int* in_sizes, int n_in,
                              void* d_out, int out_size, void* d_ws, size_t ws_size,
                              hipStream_t stream) {
    const float* x   = (const float*)d_in[0];
    const float* w1f = (const float*)d_in[1];
    const float* w2f = (const float*)d_in[2];
    const float* w1t = (const float*)d_in[3];
    const float* w2t = (const float*)d_in[4];
    const float* w1c = (const float*)d_in[5];
    const float* w2c = (const float*)d_in[6];
    float* out = (float*)d_out;

    float* ws    = (float*)d_ws;
    float* pf    = ws + PF_OFF;
    float* pt    = ws + PT_OFF;
    float* pc    = ws + PC_OFF;
    float* gates = ws + G_OFF;
    unsigned long long* cnt = (unsigned long long*)(ws + CNT_OFF);

    pool_gate_k<<<4096, 256, 0, stream>>>(x, w1f, w2f, w1t, w2t, w1c, w2c,
                                          pf, pt, pc, gates, cnt);
    apply_k<<<2048, 256, 0, stream>>>(x, gates, out);
}

// Round 15
// 252.233 us; speedup vs baseline: 1.2572x; 1.0040x over previous
//
#include <hip/hip_runtime.h>
#include <math.h>

// Problem constants
#define BB 8
#define CC 64
#define TT 512
#define FF 256

typedef float floatx4 __attribute__((ext_vector_type(4)));

constexpr int TOFF = BB * FF;                       // 2048
constexpr int COFF = BB * FF + BB * TT;             // 6144
constexpr int NSUM = BB * FF + BB * TT + BB * CC;   // 6656 floats

// ws layout (floats)
constexpr long PF_OFF  = 0;                         // Pfreq [4096][256]
constexpr long PT_OFF  = PF_OFF + 4096L * 256;      // Ptime [4096][64]
constexpr long PC_OFF  = PT_OFF + 4096L * 64;       // Pch   [4096]
constexpr long G_OFF   = PC_OFF + 4096;             // gates [NSUM]
constexpr long CNT_OFF = G_OFF + NSUM;              // 24 u64 (8B aligned)

struct PoolShm { float tr[16][257]; float fr[256]; float cw[4]; }; // 17.5 KB
struct GateShm { float s[512]; float h[512]; };                    //  4 KB
union  Shm { PoolShm p; GateShm g; };

// Agent-scope relaxed load: reads at the device coherence point (bypasses
// possibly-stale XCD-local cached copies). R14-verified correct.
__device__ __forceinline__ float aload(const float* p) {
    return __hip_atomic_load(p, __ATOMIC_RELAXED, __HIP_MEMORY_SCOPE_AGENT);
}
// Agent-scope relaxed store: WRITE-THROUGH fire-and-forget (store-class, not
// RMW-class like R14's atomicExch — no exclusive-ownership serialization).
__device__ __forceinline__ void astore(float* p, float v) {
    __hip_atomic_store(p, v, __ATOMIC_RELAXED, __HIP_MEMORY_SCOPE_AGENT);
}

// ---------------------------------------------------------------------------
// Gate tails (R14-verified): one winner block per (batch, unit).
// ---------------------------------------------------------------------------
__device__ void tail_f(const float* __restrict__ w1f, const float* __restrict__ w2f,
                       const float* __restrict__ pf, float* __restrict__ gates,
                       GateShm& gs, int b, int tid) {
    float a[8];
    #pragma unroll
    for (int i = 0; i < 8; ++i) a[i] = 0.f;
    const float* p = pf + (long)(b * 512) * 256 + tid;
    #pragma unroll 2
    for (int ch = 0; ch < 512; ch += 8) {
        #pragma unroll
        for (int i = 0; i < 8; ++i) a[i] += aload(&p[(long)(ch + i) * 256]);
    }
    gs.s[tid] = (((a[0] + a[1]) + (a[2] + a[3])) + ((a[4] + a[5]) + (a[6] + a[7])))
              * (1.f / (float)(CC * TT));
    __syncthreads();
    {
        const floatx4* wr = (const floatx4*)(w1f + (long)tid * FF);
        const floatx4* sv = (const floatx4*)gs.s;
        float c0 = 0.f, c1 = 0.f, c2 = 0.f, c3 = 0.f;
        for (int j = 0; j < FF / 4; ++j) {
            floatx4 w = wr[j], v = sv[j];
            c0 += w.x * v.x; c1 += w.y * v.y; c2 += w.z * v.z; c3 += w.w * v.w;
        }
        gs.h[tid] = fmaxf((c0 + c1) + (c2 + c3), 0.f);
    }
    __syncthreads();
    {
        const floatx4* wr = (const floatx4*)(w2f + (long)tid * FF);
        const floatx4* hv = (const floatx4*)gs.h;
        float c0 = 0.f, c1 = 0.f, c2 = 0.f, c3 = 0.f;
        for (int j = 0; j < FF / 4; ++j) {
            floatx4 w = wr[j], v = hv[j];
            c0 += w.x * v.x; c1 += w.y * v.y; c2 += w.z * v.z; c3 += w.w * v.w;
        }
        gates[b * FF + tid] = 1.f / (1.f + expf(-((c0 + c1) + (c2 + c3))));
    }
}

__device__ void tail_t(const float* __restrict__ w1t, const float* __restrict__ w2t,
                       const float* __restrict__ pt, float* __restrict__ gates,
                       GateShm& gs, int b, int tid) {
    #pragma unroll
    for (int r = 0; r < 2; ++r) {
        const int t2 = tid + r * 256;
        const float* p = pt + (long)(b * 512 + (t2 >> 6)) * 64 + (t2 & 63);
        float a0 = 0.f, a1 = 0.f, a2 = 0.f, a3 = 0.f;
        #pragma unroll 4
        for (int c = 0; c < 64; c += 4) {
            a0 += aload(&p[(long)(c + 0) * 512]);
            a1 += aload(&p[(long)(c + 1) * 512]);
            a2 += aload(&p[(long)(c + 2) * 512]);
            a3 += aload(&p[(long)(c + 3) * 512]);
        }
        gs.s[t2] = ((a0 + a1) + (a2 + a3)) * (1.f / (float)(CC * FF));
    }
    __syncthreads();
    #pragma unroll
    for (int r = 0; r < 2; ++r) {
        const int row = tid + r * 256;
        const floatx4* wr = (const floatx4*)(w1t + (long)row * TT);
        const floatx4* sv = (const floatx4*)gs.s;
        float c0 = 0.f, c1 = 0.f, c2 = 0.f, c3 = 0.f;
        for (int j = 0; j < TT / 4; ++j) {
            floatx4 w = wr[j], v = sv[j];
            c0 += w.x * v.x; c1 += w.y * v.y; c2 += w.z * v.z; c3 += w.w * v.w;
        }
        gs.h[row] = fmaxf((c0 + c1) + (c2 + c3), 0.f);
    }
    __syncthreads();
    #pragma unroll
    for (int r = 0; r < 2; ++r) {
        const int row = tid + r * 256;
        const floatx4* wr = (const floatx4*)(w2t + (long)row * TT);
        const floatx4* hv = (const floatx4*)gs.h;
        float c0 = 0.f, c1 = 0.f, c2 = 0.f, c3 = 0.f;
        for (int j = 0; j < TT / 4; ++j) {
            floatx4 w = wr[j], v = hv[j];
            c0 += w.x * v.x; c1 += w.y * v.y; c2 += w.z * v.z; c3 += w.w * v.w;
        }
        gates[TOFF + b * TT + row] = 1.f / (1.f + expf(-((c0 + c1) + (c2 + c3))));
    }
}

__device__ void tail_c(const float* __restrict__ w1c, const float* __restrict__ w2c,
                       const float* __restrict__ pc, float* __restrict__ gates,
                       GateShm& gs, int b, int tid) {
    if (tid < CC) {
        float acc = 0.f;
        #pragma unroll
        for (int j = 0; j < 8; ++j) acc += aload(&pc[b * 512 + tid * 8 + j]);
        gs.s[tid] = acc * (1.f / (float)(TT * FF));
    }
    __syncthreads();
    if (tid < CC) {
        const floatx4* wr = (const floatx4*)(w1c + (long)tid * CC);
        const floatx4* sv = (const floatx4*)gs.s;
        float c0 = 0.f, c1 = 0.f, c2 = 0.f, c3 = 0.f;
        for (int j = 0; j < CC / 4; ++j) {
            floatx4 w = wr[j], v = sv[j];
            c0 += w.x * v.x; c1 += w.y * v.y; c2 += w.z * v.z; c3 += w.w * v.w;
        }
        gs.h[tid] = fmaxf((c0 + c1) + (c2 + c3), 0.f);
    }
    __syncthreads();
    if (tid < CC) {
        const floatx4* wr = (const floatx4*)(w2c + (long)tid * CC);
        const floatx4* hv = (const floatx4*)gs.h;
        float c0 = 0.f, c1 = 0.f, c2 = 0.f, c3 = 0.f;
        for (int j = 0; j < CC / 4; ++j) {
            floatx4 w = wr[j], v = hv[j];
            c0 += w.x * v.x; c1 += w.y * v.y; c2 += w.z * v.z; c3 += w.w * v.w;
        }
        gates[COFF + b * CC + tid] = 1.f / (1.f + expf(-((c0 + c1) + (c2 + c3))));
    }
}

// ---------------------------------------------------------------------------
// Kernel 1: pool + gate tail. Identical to R14 EXCEPT the partial publish:
// atomicExch (RMW, line-serialized) -> relaxed agent-scope write-through
// STORE (fire-and-forget). s_waitcnt(0) before the ticket orders stores at
// the coherence point; mod-512 u64 ticket elects exactly one winner per
// (b,unit) regardless of counter garbage (no zeroing, no polling, no fence).
// ---------------------------------------------------------------------------
__global__ __launch_bounds__(256) void pool_gate_k(
    const float* __restrict__ x,
    const float* __restrict__ w1f, const float* __restrict__ w2f,
    const float* __restrict__ w1t, const float* __restrict__ w2t,
    const float* __restrict__ w1c, const float* __restrict__ w2c,
    float* __restrict__ pf, float* __restrict__ pt, float* __restrict__ pc,
    float* __restrict__ gates, unsigned long long* __restrict__ cnt)
{
    __shared__ Shm u;
    __shared__ int winf[3];
    const int tid  = threadIdx.x;
    const int lane = tid & 63;
    const int wid  = tid >> 6;
    const int chunk = blockIdx.x;                    // 0..4095
    const int b     = chunk >> 9;

    const floatx4* __restrict__ x4 = (const floatx4*)x;
    const long base = (long)chunk * 4096 + wid * 1024 + lane;

    float a0 = 0.f, a1 = 0.f, a2 = 0.f, a3 = 0.f;    // freq partials
    float ach[16];                                   // row sums (time)
    #pragma unroll
    for (int k = 0; k < 16; ++k) {
        floatx4 d = x4[base + k * 64];               // temporal: fill L3
        a0 += d.x; a1 += d.y; a2 += d.z; a3 += d.w;
        ach[k] = (d.x + d.y) + (d.z + d.w);
    }
    float csum = 0.f;
    #pragma unroll
    for (int k = 0; k < 16; ++k) csum += ach[k];
    #pragma unroll
    for (int o = 32; o > 0; o >>= 1) csum += __shfl_xor(csum, o, 64);

    u.p.fr[tid] = 0.f;
    #pragma unroll
    for (int k = 0; k < 16; ++k) u.p.tr[k][tid] = ach[k];
    if (lane == 0) u.p.cw[wid] = csum;
    __syncthreads();

    atomicAdd(&u.p.fr[4 * lane + 0], a0);
    atomicAdd(&u.p.fr[4 * lane + 1], a1);
    atomicAdd(&u.p.fr[4 * lane + 2], a2);
    atomicAdd(&u.p.fr[4 * lane + 3], a3);

    {   // time: row s of chunk summed by 4 threads (q), then 2 shuffles
        const int s = tid >> 2, q = tid & 3;
        float v = 0.f;
        #pragma unroll
        for (int j = 0; j < 16; ++j)
            v += u.p.tr[s & 15][(s >> 4) * 64 + q * 16 + j];
        v += __shfl_xor(v, 1, 64);
        v += __shfl_xor(v, 2, 64);
        if (q == 0) astore(&pt[chunk * 64 + s], v);  // write-through store
    }
    __syncthreads();

    astore(&pf[chunk * 256 + tid], u.p.fr[tid]);     // write-through store
    if (tid == 0)
        astore(&pc[chunk],
               (u.p.cw[0] + u.p.cw[1]) + (u.p.cw[2] + u.p.cw[3]));

    // drain: all this thread's write-through stores performed at coherence pt
    __builtin_amdgcn_s_waitcnt(0);
    __syncthreads();

    // ---- election: exactly one winner per (b,g), init-value-proof ----
    if (tid < 3) {
        unsigned long long old = atomicAdd(&cnt[b * 3 + tid], 1ULL);
        winf[tid] = (((old + 1) & 511ULL) == 0ULL);
    }
    __syncthreads();

    if (winf[0]) { tail_f(w1f, w2f, pf, gates, u.g, b, tid); __syncthreads(); }
    if (winf[1]) { tail_t(w1t, w2t, pt, gates, u.g, b, tid); __syncthreads(); }
    if (winf[2]) { tail_c(w1c, w2c, pc, gates, u.g, b, tid); }
}

// ---------------------------------------------------------------------------
// Kernel 2: apply (R7-verified, byte-identical). Descending order chases
// pool's MRU L3 content (R6: ~94% L3 hits); nt stores spare x eviction.
// The kernel boundary publishes the winners' gate stores.
// ---------------------------------------------------------------------------
__global__ __launch_bounds__(256) void apply_k(const float* __restrict__ x,
                                               const float* __restrict__ gts,
                                               float* __restrict__ out) {
    const floatx4* __restrict__ x4 = (const floatx4*)x;
    floatx4* __restrict__ o4 = (floatx4*)out;
    const long base3 = (long)blockIdx.x * 256 + threadIdx.x;   // < 2^19
    const int f4 = (int)(base3 & 63);
    const int t  = (int)((base3 >> 6) & (TT - 1));
    const int cb = (int)((base3 >> 15) & (CC - 1));
    #pragma unroll 8
    for (int k = 31; k >= 0; --k) {
        const int b = k >> 2;
        const int c = (cb + k * 16) & (CC - 1);
        const floatx4 fm = ((const floatx4*)(gts + b * FF))[f4];
        const float gadd = gts[TOFF + b * TT + t]
                         + gts[COFF + b * CC + c] + 1.0f;
        const long v = base3 + ((long)k << 19);
        floatx4 d = x4[v];                           // mostly L3 hits
        floatx4 o = d * (fm + gadd);
        __builtin_nontemporal_store(o, &o4[v]);
    }
}

extern "C" void kernel_launch(void* const* d_in, const int* in_sizes, int n_in,
                              void* d_out, int out_size, void* d_ws, size_t ws_size,
                              hipStream_t stream) {
    const float* x   = (const float*)d_in[0];
    const float* w1f = (const float*)d_in[1];
    const float* w2f = (const float*)d_in[2];
    const float* w1t = (const float*)d_in[3];
    const float* w2t = (const float*)d_in[4];
    const float* w1c = (const float*)d_in[5];
    const float* w2c = (const float*)d_in[6];
    float* out = (float*)d_out;

    float* ws    = (float*)d_ws;
    float* pf    = ws + PF_OFF;
    float* pt    = ws + PT_OFF;
    float* pc    = ws + PC_OFF;
    float* gates = ws + G_OFF;
    unsigned long long* cnt = (unsigned long long*)(ws + CNT_OFF);

    pool_gate_k<<<4096, 256, 0, stream>>>(x, w1f, w2f, w1t, w2t, w1c, w2c,
                                          pf, pt, pc, gates, cnt);
    apply_k<<<2048, 256, 0, stream>>>(x, gates, out);
}